// Round 1
// baseline (907.693 us; speedup 1.0000x reference)
//
#include <hip/hip_runtime.h>
#include <math.h>

// ---------------------------------------------------------------------------
// InfoNCE on MI355X.
// Dominant cost: T1[i,j] = tail(relu(hx[j]+hy[i]+b1)) over 512x512 pairs,
// i.e. a fused GEMM  M=262144, N=512, K=512  (A formed on the fly).
// Strategy: bf16 hi/lo split-GEMM (3 MFMA products, AlBl dropped) for
// ~fp32 accuracy at ~bf16/3 MFMA rate, epilogue fully fused (relu, @W3,
// softplus), then a single-block logsumexp reduction.
// ---------------------------------------------------------------------------

typedef __bf16 bf16x8 __attribute__((ext_vector_type(8)));
typedef float  f32x4  __attribute__((ext_vector_type(4)));

#define H    512
#define NPTS 512
#define XD   128
#define KPC  40   // padded LDS K-stride for the 32-wide A chunk (32+8)

// ---------------- prep: hx, hy(+b1), W2 -> transposed bf16 hi/lo ----------
__global__ __launch_bounds__(256) void prep_kernel(
    const float* __restrict__ x, const float* __restrict__ y,
    const float* __restrict__ W1x, const float* __restrict__ W1y,
    const float* __restrict__ b1, const float* __restrict__ W2,
    float* __restrict__ hx, float* __restrict__ hy,
    __bf16* __restrict__ w2h, __bf16* __restrict__ w2l) {
  __shared__ float xr[XD];
  const int b = blockIdx.x;
  const int t = threadIdx.x;
  if (b < 2 * NPTS) {
    const bool isY = (b >= NPTS);
    const int row = isY ? b - NPTS : b;
    const float* src = isY ? y : x;      // [NPTS][XD]
    const float* W   = isY ? W1y : W1x;  // [XD][H]
    if (t < XD) xr[t] = src[row * XD + t];
    __syncthreads();
    for (int c = t; c < H; c += 256) {
      float s = 0.f;
#pragma unroll
      for (int k = 0; k < XD; ++k) s = fmaf(xr[k], W[k * H + c], s);
      if (isY) hy[row * H + c] = s + b1[c];   // fold b1 into hy
      else     hx[row * H + c] = s;
    }
  } else {
    // W2 is [k][n] row-major; emit W2T hi/lo as [n][k] bf16 (k contiguous)
    const int n = b - 2 * NPTS;
    for (int k = t; k < H; k += 256) {
      float v = W2[k * H + n];
      __bf16 hi = (__bf16)v;
      float lo = v - (float)hi;
      w2h[n * H + k] = hi;
      w2l[n * H + k] = (__bf16)lo;
    }
  }
}

// ---------------- pair GEMM + fused tail -> T1 (post-softplus) ------------
// grid 64x64 blocks (i-tile, j-tile of 8 each -> M-tile = 64 pairs),
// 512 threads = 8 waves; wave w covers all 64 rows x cols [w*64, w*64+64).
__global__ __launch_bounds__(512, 2) void pair_kernel(
    const float* __restrict__ hx, const float* __restrict__ hy,
    const __bf16* __restrict__ w2h, const __bf16* __restrict__ w2l,
    const float* __restrict__ b2, const float* __restrict__ W3,
    const float* __restrict__ b3, float* __restrict__ T1) {
  __shared__ __align__(16) __bf16 Ah[64 * KPC];
  __shared__ __align__(16) __bf16 Al[64 * KPC];
  __shared__ float red[8][64];

  const int t    = threadIdx.x;
  const int i0   = (blockIdx.x >> 6) * 8;
  const int j0   = (blockIdx.x & 63) * 8;
  const int wave = t >> 6;
  const int lane = t & 63;
  const int col  = lane & 15;   // MFMA: A row / B col / D col
  const int quad = lane >> 4;   // MFMA: k-group / D row group
  const int nbase = wave * 64;

  const int sk  = t & 31;       // staging: k within chunk
  const int sm0 = t >> 5;       // staging: base row (0..15)

  f32x4 acc[4][4] = {};

  for (int kc = 0; kc < 16; ++kc) {
    const int k0 = kc * 32;
    __syncthreads();  // previous chunk's LDS reads done
#pragma unroll
    for (int r = 0; r < 4; ++r) {
      const int m = sm0 + r * 16;            // pair row in tile
      const int ti = m >> 3, tj = m & 7;
      float a = hx[(j0 + tj) * H + k0 + sk] + hy[(i0 + ti) * H + k0 + sk];
      a = a > 0.f ? a : 0.f;                 // first relu
      __bf16 hi = (__bf16)a;
      float lo = a - (float)hi;
      Ah[m * KPC + sk] = hi;
      Al[m * KPC + sk] = (__bf16)lo;
    }
    __syncthreads();

    bf16x8 Bh[4], Bl[4], Afh[4], Afl[4];
    const int kq = quad * 8;
#pragma unroll
    for (int tn = 0; tn < 4; ++tn) {
      const int off = (nbase + tn * 16 + col) * H + k0 + kq;
      Bh[tn] = *(const bf16x8*)(w2h + off);
      Bl[tn] = *(const bf16x8*)(w2l + off);
    }
#pragma unroll
    for (int tm = 0; tm < 4; ++tm) {
      const int off = (tm * 16 + col) * KPC + kq;
      Afh[tm] = *(const bf16x8*)(Ah + off);
      Afl[tm] = *(const bf16x8*)(Al + off);
    }
#pragma unroll
    for (int tm = 0; tm < 4; ++tm)
#pragma unroll
      for (int tn = 0; tn < 4; ++tn) {
        acc[tm][tn] = __builtin_amdgcn_mfma_f32_16x16x32_bf16(Afh[tm], Bh[tn], acc[tm][tn], 0, 0, 0);
        acc[tm][tn] = __builtin_amdgcn_mfma_f32_16x16x32_bf16(Afh[tm], Bl[tn], acc[tm][tn], 0, 0, 0);
        acc[tm][tn] = __builtin_amdgcn_mfma_f32_16x16x32_bf16(Afl[tm], Bh[tn], acc[tm][tn], 0, 0, 0);
      }
  }

  // epilogue: v = relu(h2 + b2); row_sum += v*W3; reduce; softplus
  float bb[4], w3v[4];
#pragma unroll
  for (int tn = 0; tn < 4; ++tn) {
    const int n = nbase + tn * 16 + col;
    bb[tn]  = b2[n];
    w3v[tn] = W3[n];
  }
#pragma unroll
  for (int tm = 0; tm < 4; ++tm) {
#pragma unroll
    for (int reg = 0; reg < 4; ++reg) {
      float p = 0.f;
#pragma unroll
      for (int tn = 0; tn < 4; ++tn) {
        float v = acc[tm][tn][reg] + bb[tn];
        v = v > 0.f ? v : 0.f;               // second relu
        p = fmaf(v, w3v[tn], p);
      }
      // sum over the 16 'col' lanes (bits 0..3 of lane)
      p += __shfl_xor(p, 1);
      p += __shfl_xor(p, 2);
      p += __shfl_xor(p, 4);
      p += __shfl_xor(p, 8);
      if (col == 0) red[wave][tm * 16 + quad * 4 + reg] = p;
    }
  }
  __syncthreads();
  if (t < 64) {
    float s = b3[0];
#pragma unroll
    for (int w = 0; w < 8; ++w) s += red[w][t];
    // stable softplus
    const float sp = s > 0.f ? s + log1pf(expf(-s)) : log1pf(expf(s));
    const int ti = t >> 3, tj = t & 7;
    T1[(i0 + ti) * NPTS + (j0 + tj)] = sp;   // row = i (hy), col = j (hx)
  }
}

// ---------------- final reduction: mean(diag) - (mean(lse) - log N) -------
__global__ __launch_bounds__(1024) void reduce_kernel(
    const float* __restrict__ T1, float* __restrict__ out) {
  __shared__ float slse[16], st0[16];
  const int t = threadIdx.x;
  const int wave = t >> 6, lane = t & 63;
  float wlse = 0.f, wt0 = 0.f;
  for (int g = 0; g < 32; ++g) {
    const int r = wave + g * 16;
    float se = 0.f;
#pragma unroll
    for (int q = 0; q < 8; ++q) se += expf(T1[r * NPTS + lane + q * 64]);
#pragma unroll
    for (int off = 1; off < 64; off <<= 1) se += __shfl_xor(se, off);
    if (lane == 0) {
      wlse += logf(se);
      wt0  += T1[r * NPTS + r];   // diag == T0
    }
  }
  if (lane == 0) { slse[wave] = wlse; st0[wave] = wt0; }
  __syncthreads();
  if (t == 0) {
    float a = 0.f, b = 0.f;
    for (int w = 0; w < 16; ++w) { a += st0[w]; b += slse[w]; }
    out[0] = a / 512.0f - b / 512.0f + logf(512.0f);
  }
}

// ---------------------------------------------------------------------------
extern "C" void kernel_launch(void* const* d_in, const int* in_sizes, int n_in,
                              void* d_out, int out_size, void* d_ws, size_t ws_size,
                              hipStream_t stream) {
  const float* x   = (const float*)d_in[0];
  const float* y   = (const float*)d_in[1];
  const float* W1x = (const float*)d_in[2];
  const float* W1y = (const float*)d_in[3];
  const float* b1  = (const float*)d_in[4];
  const float* W2  = (const float*)d_in[5];
  const float* b2  = (const float*)d_in[6];
  const float* W3  = (const float*)d_in[7];
  const float* b3  = (const float*)d_in[8];

  float* ws = (float*)d_ws;
  float* hx = ws;                         // 512*512 f32
  float* hy = ws + 262144;                // 512*512 f32
  float* T1 = ws + 524288;                // 512*512 f32
  __bf16* w2h = (__bf16*)(ws + 786432);   // 512*512 bf16
  __bf16* w2l = w2h + 262144;             // 512*512 bf16
  float* out = (float*)d_out;

  hipLaunchKernelGGL(prep_kernel, dim3(1536), dim3(256), 0, stream,
                     x, y, W1x, W1y, b1, W2, hx, hy, w2h, w2l);
  hipLaunchKernelGGL(pair_kernel, dim3(4096), dim3(512), 0, stream,
                     hx, hy, w2h, w2l, b2, W3, b3, T1);
  hipLaunchKernelGGL(reduce_kernel, dim3(1), dim3(1024), 0, stream, T1, out);
}

// Round 2
// 598.656 us; speedup vs baseline: 1.5162x; 1.5162x over previous
//
#include <hip/hip_runtime.h>
#include <math.h>

// ---------------------------------------------------------------------------
// InfoNCE on MI355X — v2.
// T1[i,j] = tail(relu(hx[j]+hy[i]+b1)) over 512x512 pairs = fused GEMM
// M=262144, N=512, K=512, A formed on the fly. bf16 hi/lo split (3 MFMA
// products). v2: K-chunk=64, double-buffered LDS, ONE barrier per chunk,
// register-prefetched A staging (float4 + ds_write_b128, conflict-free
// 144B stride), W2 repacked fragment-major (1KB contiguous B-frag loads),
// parallel lse reduction.
// ---------------------------------------------------------------------------

typedef __bf16 bf16x8 __attribute__((ext_vector_type(8)));
typedef float  f32x4  __attribute__((ext_vector_type(4)));

#define H    512
#define NPTS 512
#define XD   128
#define KP   72   // A-tile LDS row stride (elems): 144 B = 36 banks -> uniform

// ---------------- prep: hx, hy(+b1); W2 -> fragment-major bf16 hi/lo ------
__global__ __launch_bounds__(256) void prep_kernel(
    const float* __restrict__ x, const float* __restrict__ y,
    const float* __restrict__ W1x, const float* __restrict__ W1y,
    const float* __restrict__ b1, const float* __restrict__ W2,
    float* __restrict__ hx, float* __restrict__ hy,
    __bf16* __restrict__ w2h, __bf16* __restrict__ w2l) {
  __shared__ float xr[XD];
  const int b = blockIdx.x;
  const int t = threadIdx.x;
  if (b < 2 * NPTS) {
    const bool isY = (b >= NPTS);
    const int row = isY ? b - NPTS : b;
    const float* src = isY ? y : x;      // [NPTS][XD]
    const float* W   = isY ? W1y : W1x;  // [XD][H]
    if (t < XD) xr[t] = src[row * XD + t];
    __syncthreads();
    for (int c = t; c < H; c += 256) {
      float s = 0.f;
#pragma unroll
      for (int k = 0; k < XD; ++k) s = fmaf(xr[k], W[k * H + c], s);
      if (isY) hy[row * H + c] = s + b1[c];   // fold b1 into hy
      else     hx[row * H + c] = s;
    }
  } else {
    // W2[k][n] -> fragment-major: idx = ((n>>4)*16 + (k>>5))*512
    //                                   + (n&15)*32 + (k&31)
    // so a wave's B-frag load (16 cols x 4 quads x 8 elems) is 1 KB contiguous.
    const int n = b - 2 * NPTS;
    for (int k = t; k < H; k += 256) {
      float v = W2[k * H + n];
      __bf16 hi = (__bf16)v;
      float lo = v - (float)hi;
      const int idx = (((n >> 4) * 16) + (k >> 5)) * 512 + (n & 15) * 32 + (k & 31);
      w2h[idx] = hi;
      w2l[idx] = (__bf16)lo;
    }
  }
}

// ---------------- pair GEMM + fused tail -> T1 (post-softplus) ------------
// grid 64x64 blocks (8i x 8j -> M-tile 64 pairs), 512 threads = 8 waves;
// wave w: all 64 rows x cols [w*64, w*64+64). K pipelined in 64-chunks.
__global__ __launch_bounds__(512, 2) void pair_kernel(
    const float* __restrict__ hx, const float* __restrict__ hy,
    const __bf16* __restrict__ w2h, const __bf16* __restrict__ w2l,
    const float* __restrict__ b2, const float* __restrict__ W3,
    const float* __restrict__ b3, float* __restrict__ T1) {
  __shared__ __align__(16) __bf16 Ah[2][64 * KP];
  __shared__ __align__(16) __bf16 Al[2][64 * KP];
  __shared__ float red[8][64];

  const int t    = threadIdx.x;
  const int i0   = (blockIdx.x >> 6) * 8;
  const int j0   = (blockIdx.x & 63) * 8;
  const int wave = t >> 6;
  const int lane = t & 63;
  const int col  = lane & 15;
  const int quad = lane >> 4;

  // staging: thread handles row sm (0..63), k-segment seg (8 elems)
  const int sm  = t >> 3;
  const int seg = t & 7;
  const float* hxp = hx + (j0 + (sm & 7)) * H + seg * 8;   // tj = sm&7
  const float* hyp = hy + (i0 + (sm >> 3)) * H + seg * 8;  // ti = sm>>3
  const int awoff = sm * KP + seg * 8;

  const int boff = col * 32 + quad * 8;   // lane offset inside 1KB B-frag
  const int g0   = wave * 4;              // B n-group base (n>>4)

  f32x4 acc[4][4] = {};

  auto stage = [&](int buf, float4 X0, float4 X1, float4 Y0, float4 Y1) {
    float a[8] = {X0.x + Y0.x, X0.y + Y0.y, X0.z + Y0.z, X0.w + Y0.w,
                  X1.x + Y1.x, X1.y + Y1.y, X1.z + Y1.z, X1.w + Y1.w};
    bf16x8 hv, lv;
#pragma unroll
    for (int e = 0; e < 8; ++e) {
      float v = a[e] > 0.f ? a[e] : 0.f;   // first relu
      __bf16 hi = (__bf16)v;
      hv[e] = hi;
      lv[e] = (__bf16)(v - (float)hi);
    }
    *(bf16x8*)(&Ah[buf][awoff]) = hv;
    *(bf16x8*)(&Al[buf][awoff]) = lv;
  };

  // prologue: stage chunk 0
  {
    float4 x0 = *(const float4*)(hxp);
    float4 x1 = *(const float4*)(hxp + 4);
    float4 y0 = *(const float4*)(hyp);
    float4 y1 = *(const float4*)(hyp + 4);
    stage(0, x0, x1, y0, y1);
  }
  __syncthreads();

#pragma unroll 2
  for (int kc = 0; kc < 8; ++kc) {
    const int cur = kc & 1;
    // prefetch next A chunk into registers (consumed after MFMA phase)
    float4 nx0, nx1, ny0, ny1;
    if (kc < 7) {
      const float* px = hxp + (kc + 1) * 64;
      const float* py = hyp + (kc + 1) * 64;
      nx0 = *(const float4*)px; nx1 = *(const float4*)(px + 4);
      ny0 = *(const float4*)py; ny1 = *(const float4*)(py + 4);
    }
    // B frags for both k-steps of this chunk (each load = 1KB contiguous)
    bf16x8 Bh[2][4], Bl[2][4];
#pragma unroll
    for (int s = 0; s < 2; ++s)
#pragma unroll
      for (int tn = 0; tn < 4; ++tn) {
        const int base = (((g0 + tn) * 16) + (kc * 2 + s)) * 512 + boff;
        Bh[s][tn] = *(const bf16x8*)(w2h + base);
        Bl[s][tn] = *(const bf16x8*)(w2l + base);
      }
#pragma unroll
    for (int s = 0; s < 2; ++s) {
      bf16x8 Afh[4], Afl[4];
      const int ko = s * 32 + quad * 8;
#pragma unroll
      for (int tm = 0; tm < 4; ++tm) {
        const int off = (tm * 16 + col) * KP + ko;
        Afh[tm] = *(const bf16x8*)(&Ah[cur][off]);
        Afl[tm] = *(const bf16x8*)(&Al[cur][off]);
      }
#pragma unroll
      for (int tm = 0; tm < 4; ++tm)
#pragma unroll
        for (int tn = 0; tn < 4; ++tn) {
          acc[tm][tn] = __builtin_amdgcn_mfma_f32_16x16x32_bf16(Afh[tm], Bh[s][tn], acc[tm][tn], 0, 0, 0);
          acc[tm][tn] = __builtin_amdgcn_mfma_f32_16x16x32_bf16(Afh[tm], Bl[s][tn], acc[tm][tn], 0, 0, 0);
          acc[tm][tn] = __builtin_amdgcn_mfma_f32_16x16x32_bf16(Afl[tm], Bh[s][tn], acc[tm][tn], 0, 0, 0);
        }
    }
    // write next chunk into the other buffer (its readers synced last barrier)
    if (kc < 7) stage(cur ^ 1, nx0, nx1, ny0, ny1);
    __syncthreads();
  }

  // epilogue: v = relu(h2 + b2); p = v*W3; reduce over 16 col-lanes; softplus
  float bb[4], w3v[4];
#pragma unroll
  for (int tn = 0; tn < 4; ++tn) {
    const int n = wave * 64 + tn * 16 + col;
    bb[tn]  = b2[n];
    w3v[tn] = W3[n];
  }
#pragma unroll
  for (int tm = 0; tm < 4; ++tm) {
#pragma unroll
    for (int reg = 0; reg < 4; ++reg) {
      float p = 0.f;
#pragma unroll
      for (int tn = 0; tn < 4; ++tn) {
        float v = acc[tm][tn][reg] + bb[tn];
        v = v > 0.f ? v : 0.f;               // second relu
        p = fmaf(v, w3v[tn], p);
      }
      p += __shfl_xor(p, 1);
      p += __shfl_xor(p, 2);
      p += __shfl_xor(p, 4);
      p += __shfl_xor(p, 8);
      if (col == 0) red[wave][tm * 16 + quad * 4 + reg] = p;
    }
  }
  __syncthreads();
  if (t < 64) {
    float s = b3[0];
#pragma unroll
    for (int w = 0; w < 8; ++w) s += red[w][t];
    const float sp = s > 0.f ? s + log1pf(expf(-s)) : log1pf(expf(s));
    const int ti = t >> 3, tj = t & 7;
    T1[(i0 + ti) * NPTS + (j0 + tj)] = sp;   // row = i (hy), col = j (hx)
  }
}

// ---------------- parallel lse: one wave per row --------------------------
__global__ __launch_bounds__(512) void rowlse_kernel(
    const float* __restrict__ T1, float* __restrict__ lse) {
  const int r    = blockIdx.x * 8 + (threadIdx.x >> 6);
  const int lane = threadIdx.x & 63;
  const float* row = T1 + r * NPTS;
  float se = 0.f;
#pragma unroll
  for (int q = 0; q < 8; ++q) se += expf(row[lane + q * 64]);
#pragma unroll
  for (int off = 1; off < 64; off <<= 1) se += __shfl_xor(se, off);
  if (lane == 0) lse[r] = logf(se);
}

// ---------------- final: mean(diag) - (mean(lse) - log N) -----------------
__global__ __launch_bounds__(512) void final_kernel(
    const float* __restrict__ T1, const float* __restrict__ lse,
    float* __restrict__ out) {
  __shared__ float s1[8], s2[8];
  const int t = threadIdx.x, lane = t & 63, w = t >> 6;
  float a = T1[t * NPTS + t];   // diag == T0
  float b = lse[t];
#pragma unroll
  for (int off = 1; off < 64; off <<= 1) {
    a += __shfl_xor(a, off);
    b += __shfl_xor(b, off);
  }
  if (lane == 0) { s1[w] = a; s2[w] = b; }
  __syncthreads();
  if (t == 0) {
    float sa = 0.f, sb = 0.f;
#pragma unroll
    for (int i = 0; i < 8; ++i) { sa += s1[i]; sb += s2[i]; }
    out[0] = sa / 512.0f - sb / 512.0f + logf(512.0f);
  }
}

// ---------------------------------------------------------------------------
extern "C" void kernel_launch(void* const* d_in, const int* in_sizes, int n_in,
                              void* d_out, int out_size, void* d_ws, size_t ws_size,
                              hipStream_t stream) {
  const float* x   = (const float*)d_in[0];
  const float* y   = (const float*)d_in[1];
  const float* W1x = (const float*)d_in[2];
  const float* W1y = (const float*)d_in[3];
  const float* b1  = (const float*)d_in[4];
  const float* W2  = (const float*)d_in[5];
  const float* b2  = (const float*)d_in[6];
  const float* W3  = (const float*)d_in[7];
  const float* b3  = (const float*)d_in[8];

  float* ws = (float*)d_ws;
  float* hx = ws;                         // 512*512 f32
  float* hy = ws + 262144;                // 512*512 f32
  float* T1 = ws + 524288;                // 512*512 f32
  __bf16* w2h = (__bf16*)(ws + 786432);   // 512*512 bf16 (fragment-major)
  __bf16* w2l = w2h + 262144;             // 512*512 bf16
  float* lse = ws + 786432 + 131072;      // 512 f32
  float* out = (float*)d_out;

  hipLaunchKernelGGL(prep_kernel, dim3(1536), dim3(256), 0, stream,
                     x, y, W1x, W1y, b1, W2, hx, hy, w2h, w2l);
  hipLaunchKernelGGL(pair_kernel, dim3(4096), dim3(512), 0, stream,
                     hx, hy, w2h, w2l, b2, W3, b3, T1);
  hipLaunchKernelGGL(rowlse_kernel, dim3(64), dim3(512), 0, stream, T1, lse);
  hipLaunchKernelGGL(final_kernel, dim3(1), dim3(512), 0, stream, T1, lse, out);
}

// Round 3
// 500.310 us; speedup vs baseline: 1.8143x; 1.1966x over previous
//
#include <hip/hip_runtime.h>
#include <math.h>

// ---------------------------------------------------------------------------
// InfoNCE on MI355X — v3.
// T1[i,j] = tail(relu(hx[j]+hy[i]+b1)) = fused GEMM M=262144, N=512, K=512,
// A formed on the fly; bf16 hi/lo split (3 MFMA products, AlBl dropped).
// v3 vs v2: M-tile 128/block (8 m-tiles per wave -> 2x B-frag register reuse,
// halves B L2 traffic), K-step=32 double-buffered LDS with cross-barrier
// prefetch of BOTH B-frags and A staging loads (pre-barrier vmcnt drain hits
// loads issued a full k-step earlier -> latency hidden).
// ---------------------------------------------------------------------------

typedef __bf16 bf16x8 __attribute__((ext_vector_type(8)));
typedef float  f32x4  __attribute__((ext_vector_type(4)));

#define H    512
#define NPTS 512
#define XD   128
#define SP   40   // LDS row stride (elems) for 32-k chunk: 80B -> balanced banks

// ---------------- prep: hx, hy(+b1); W2 -> fragment-major bf16 hi/lo ------
__global__ __launch_bounds__(256) void prep_kernel(
    const float* __restrict__ x, const float* __restrict__ y,
    const float* __restrict__ W1x, const float* __restrict__ W1y,
    const float* __restrict__ b1, const float* __restrict__ W2,
    float* __restrict__ hx, float* __restrict__ hy,
    __bf16* __restrict__ w2h, __bf16* __restrict__ w2l) {
  __shared__ float xr[XD];
  const int b = blockIdx.x;
  const int t = threadIdx.x;
  if (b < 2 * NPTS) {
    const bool isY = (b >= NPTS);
    const int row = isY ? b - NPTS : b;
    const float* src = isY ? y : x;      // [NPTS][XD]
    const float* W   = isY ? W1y : W1x;  // [XD][H]
    if (t < XD) xr[t] = src[row * XD + t];
    __syncthreads();
    for (int c = t; c < H; c += 256) {
      float s = 0.f;
#pragma unroll
      for (int k = 0; k < XD; ++k) s = fmaf(xr[k], W[k * H + c], s);
      if (isY) hy[row * H + c] = s + b1[c];   // fold b1 into hy
      else     hx[row * H + c] = s;
    }
  } else {
    // W2[k][n] -> fragment-major: idx = ((n>>4)*16 + (k>>5))*512
    //                                   + (n&15)*32 + (k&31)
    // a wave's B-frag load (16 cols x 4 quads x 8 elems) = 1 KB contiguous.
    const int n = b - 2 * NPTS;
    for (int k = t; k < H; k += 256) {
      float v = W2[k * H + n];
      __bf16 hi = (__bf16)v;
      float lo = v - (float)hi;
      const int idx = (((n >> 4) * 16) + (k >> 5)) * 512 + (n & 15) * 32 + (k & 31);
      w2h[idx] = hi;
      w2l[idx] = (__bf16)lo;
    }
  }
}

// ---------------- pair GEMM + fused tail -> T1 (post-softplus) ------------
// grid 2048 = 32 i-groups x 64 j-groups; M-tile = 128 pairs (16 i x 8 j).
// 512 threads = 8 waves; wave w: all 128 rows x cols [w*64, w*64+64)
// (8 m-tiles x 4 n-tiles, acc[8][4]). K in 16 steps of 32, LDS double-buffer.
__global__ __launch_bounds__(512, 2) void pair_kernel(
    const float* __restrict__ hx, const float* __restrict__ hy,
    const __bf16* __restrict__ w2h, const __bf16* __restrict__ w2l,
    const float* __restrict__ b2, const float* __restrict__ W3,
    const float* __restrict__ b3, float* __restrict__ T1) {
  __shared__ __align__(16) __bf16 Ah[2][128 * SP];
  __shared__ __align__(16) __bf16 Al[2][128 * SP];
  __shared__ float red[8][128];

  const int t    = threadIdx.x;
  const int i0   = (blockIdx.x >> 6) * 16;
  const int j0   = (blockIdx.x & 63) * 8;
  const int wave = t >> 6;
  const int lane = t & 63;
  const int col  = lane & 15;
  const int quad = lane >> 4;

  // staging: thread -> row sm (0..127), k-seg seg (8 elems of the 32-k chunk)
  const int sm  = t >> 2;
  const int seg = t & 3;
  const float* hxp = hx + (j0 + (sm & 7)) * H + seg * 8;   // tj = sm&7
  const float* hyp = hy + (i0 + (sm >> 3)) * H + seg * 8;  // ti = sm>>3
  const int awoff = sm * SP + seg * 8;

  const int boff = col * 32 + quad * 8;   // lane offset inside 1KB B-frag
  const int g0   = wave * 4;              // B n-group base (n>>4)

  f32x4 acc[8][4] = {};
  bf16x8 Bh[2][4], Bl[2][4];

  auto stage = [&](int buf, float4 X0, float4 X1, float4 Y0, float4 Y1) {
    float a[8] = {X0.x + Y0.x, X0.y + Y0.y, X0.z + Y0.z, X0.w + Y0.w,
                  X1.x + Y1.x, X1.y + Y1.y, X1.z + Y1.z, X1.w + Y1.w};
    bf16x8 hv, lv;
#pragma unroll
    for (int e = 0; e < 8; ++e) {
      float v = a[e] > 0.f ? a[e] : 0.f;   // first relu
      __bf16 hi = (__bf16)v;
      hv[e] = hi;
      lv[e] = (__bf16)(v - (float)hi);
    }
    *(bf16x8*)(&Ah[buf][awoff]) = hv;
    *(bf16x8*)(&Al[buf][awoff]) = lv;
  };

  // prologue: stage k-step 0, preload B for k-step 0
  {
    float4 x0 = *(const float4*)(hxp);
    float4 x1 = *(const float4*)(hxp + 4);
    float4 y0 = *(const float4*)(hyp);
    float4 y1 = *(const float4*)(hyp + 4);
    stage(0, x0, x1, y0, y1);
  }
#pragma unroll
  for (int tn = 0; tn < 4; ++tn) {
    const int base = ((g0 + tn) * 16) * 512 + boff;
    Bh[0][tn] = *(const bf16x8*)(w2h + base);
    Bl[0][tn] = *(const bf16x8*)(w2l + base);
  }
  __syncthreads();

#pragma unroll 2
  for (int ks = 0; ks < 16; ++ks) {
    const int cur = ks & 1;
    // prefetch staging loads for k-step ks+1 (consumed after MFMA phase)
    float4 nx0, nx1, ny0, ny1;
    if (ks < 15) {
      const float* px = hxp + (ks + 1) * 32;
      const float* py = hyp + (ks + 1) * 32;
      nx0 = *(const float4*)px; nx1 = *(const float4*)(px + 4);
      ny0 = *(const float4*)py; ny1 = *(const float4*)(py + 4);
    }
    // prefetch B frags for k-step ks+1 (used after next barrier)
    if (ks < 15) {
#pragma unroll
      for (int tn = 0; tn < 4; ++tn) {
        const int base = (((g0 + tn) * 16) + (ks + 1)) * 512 + boff;
        Bh[cur ^ 1][tn] = *(const bf16x8*)(w2h + base);
        Bl[cur ^ 1][tn] = *(const bf16x8*)(w2l + base);
      }
    }
    // MFMA phase: 8 m-tiles x 4 n-tiles x 3 products with B[cur]
#pragma unroll
    for (int tm = 0; tm < 8; ++tm) {
      const int off = (tm * 16 + col) * SP + quad * 8;
      bf16x8 Afh = *(const bf16x8*)(&Ah[cur][off]);
      bf16x8 Afl = *(const bf16x8*)(&Al[cur][off]);
#pragma unroll
      for (int tn = 0; tn < 4; ++tn) {
        acc[tm][tn] = __builtin_amdgcn_mfma_f32_16x16x32_bf16(Afh, Bh[cur][tn], acc[tm][tn], 0, 0, 0);
        acc[tm][tn] = __builtin_amdgcn_mfma_f32_16x16x32_bf16(Afh, Bl[cur][tn], acc[tm][tn], 0, 0, 0);
        acc[tm][tn] = __builtin_amdgcn_mfma_f32_16x16x32_bf16(Afl, Bh[cur][tn], acc[tm][tn], 0, 0, 0);
      }
    }
    // write next chunk into the other LDS buffer (readers synced 1 barrier ago)
    if (ks < 15) stage(cur ^ 1, nx0, nx1, ny0, ny1);
    __syncthreads();
  }

  // epilogue: v = relu(h2 + b2); p = v*W3; reduce over 16 col-lanes; softplus
  float bb[4], w3v[4];
#pragma unroll
  for (int tn = 0; tn < 4; ++tn) {
    const int n = wave * 64 + tn * 16 + col;
    bb[tn]  = b2[n];
    w3v[tn] = W3[n];
  }
#pragma unroll
  for (int tm = 0; tm < 8; ++tm) {
#pragma unroll
    for (int reg = 0; reg < 4; ++reg) {
      float p = 0.f;
#pragma unroll
      for (int tn = 0; tn < 4; ++tn) {
        float v = acc[tm][tn][reg] + bb[tn];
        v = v > 0.f ? v : 0.f;               // second relu
        p = fmaf(v, w3v[tn], p);
      }
      p += __shfl_xor(p, 1);
      p += __shfl_xor(p, 2);
      p += __shfl_xor(p, 4);
      p += __shfl_xor(p, 8);
      if (col == 0) red[wave][tm * 16 + quad * 4 + reg] = p;
    }
  }
  __syncthreads();
  if (t < 128) {
    float s = b3[0];
#pragma unroll
    for (int w = 0; w < 8; ++w) s += red[w][t];
    const float sp = s > 0.f ? s + log1pf(expf(-s)) : log1pf(expf(s));
    const int ti = t >> 3, tj = t & 7;
    T1[(i0 + ti) * NPTS + (j0 + tj)] = sp;   // row = i (hy), col = j (hx)
  }
}

// ---------------- parallel lse: one wave per row --------------------------
__global__ __launch_bounds__(512) void rowlse_kernel(
    const float* __restrict__ T1, float* __restrict__ lse) {
  const int r    = blockIdx.x * 8 + (threadIdx.x >> 6);
  const int lane = threadIdx.x & 63;
  const float* row = T1 + r * NPTS;
  float se = 0.f;
#pragma unroll
  for (int q = 0; q < 8; ++q) se += expf(row[lane + q * 64]);
#pragma unroll
  for (int off = 1; off < 64; off <<= 1) se += __shfl_xor(se, off);
  if (lane == 0) lse[r] = logf(se);
}

// ---------------- final: mean(diag) - (mean(lse) - log N) -----------------
__global__ __launch_bounds__(512) void final_kernel(
    const float* __restrict__ T1, const float* __restrict__ lse,
    float* __restrict__ out) {
  __shared__ float s1[8], s2[8];
  const int t = threadIdx.x, lane = t & 63, w = t >> 6;
  float a = T1[t * NPTS + t];   // diag == T0
  float b = lse[t];
#pragma unroll
  for (int off = 1; off < 64; off <<= 1) {
    a += __shfl_xor(a, off);
    b += __shfl_xor(b, off);
  }
  if (lane == 0) { s1[w] = a; s2[w] = b; }
  __syncthreads();
  if (t == 0) {
    float sa = 0.f, sb = 0.f;
#pragma unroll
    for (int i = 0; i < 8; ++i) { sa += s1[i]; sb += s2[i]; }
    out[0] = sa / 512.0f - sb / 512.0f + logf(512.0f);
  }
}

// ---------------------------------------------------------------------------
extern "C" void kernel_launch(void* const* d_in, const int* in_sizes, int n_in,
                              void* d_out, int out_size, void* d_ws, size_t ws_size,
                              hipStream_t stream) {
  const float* x   = (const float*)d_in[0];
  const float* y   = (const float*)d_in[1];
  const float* W1x = (const float*)d_in[2];
  const float* W1y = (const float*)d_in[3];
  const float* b1  = (const float*)d_in[4];
  const float* W2  = (const float*)d_in[5];
  const float* b2  = (const float*)d_in[6];
  const float* W3  = (const float*)d_in[7];
  const float* b3  = (const float*)d_in[8];

  float* ws = (float*)d_ws;
  float* hx = ws;                         // 512*512 f32
  float* hy = ws + 262144;                // 512*512 f32
  float* T1 = ws + 524288;                // 512*512 f32
  __bf16* w2h = (__bf16*)(ws + 786432);   // 512*512 bf16 (fragment-major)
  __bf16* w2l = w2h + 262144;             // 512*512 bf16
  float* lse = ws + 786432 + 131072;      // 512 f32
  float* out = (float*)d_out;

  hipLaunchKernelGGL(prep_kernel, dim3(1536), dim3(256), 0, stream,
                     x, y, W1x, W1y, b1, W2, hx, hy, w2h, w2l);
  hipLaunchKernelGGL(pair_kernel, dim3(2048), dim3(512), 0, stream,
                     hx, hy, w2h, w2l, b2, W3, b3, T1);
  hipLaunchKernelGGL(rowlse_kernel, dim3(64), dim3(512), 0, stream, T1, lse);
  hipLaunchKernelGGL(final_kernel, dim3(1), dim3(512), 0, stream, T1, lse, out);
}